// Round 4
// baseline (400.847 us; speedup 1.0000x reference)
//
#include <hip/hip_runtime.h>
#include <hip/hip_cooperative_groups.h>

namespace cg = cooperative_groups;

#define KD 1536
#define ND 3072
#define MD 784
#define MPAD 832
#define TT 16
#define GRID_N 768              // 16 t x 48 channel-chunks; 3 blocks/CU on 256 CUs

typedef __attribute__((ext_vector_type(8))) short short8;
typedef __attribute__((ext_vector_type(4))) float floatx4;

__device__ __forceinline__ unsigned short f2bf(float f) {
    unsigned int x = __float_as_uint(f);
    unsigned int r = (x + 0x7fffu + ((x >> 16) & 1u)) >> 16;
    return (unsigned short)r;
}

// =============== phase A: roi + packA + packB + zerofill ===============
__device__ void phaseA(char* smraw,
                       const float* __restrict__ y, const float* __restrict__ x_t,
                       const float* __restrict__ rois, const float* __restrict__ conv_w,
                       unsigned short* __restrict__ Ap, unsigned short* __restrict__ Bp,
                       float* __restrict__ mr) {
    __shared__ float wx0s[14], wx1s[14], wy0s[14], wy1s[14];
    __shared__ int x0s[14], x1s[14], y0s[14], y1s[14], vxs[14], vys[14];
    float* sm = (float*)smraw;                  // 64*197 floats = 50,432 B
    const int bid = blockIdx.x;
    const int tid = threadIdx.x;

    // ---- ROI align for (t, oc): x_t -> mr[m][ND], m = t*49 + ij
    const int t = bid / 48;
    const int o0 = (bid % 48) * 64;

    if (tid < 14) {
        float b0 = rois[t * 4 + 0] * 0.0625f, b1 = rois[t * 4 + 1] * 0.0625f;
        float b2 = rois[t * 4 + 2] * 0.0625f, b3 = rois[t * 4 + 3] * 0.0625f;
        float rw = fmaxf(b2 - b0, 1.0f), rh = fmaxf(b3 - b1, 1.0f);
        float bw = rw * (1.0f / 7.0f), bh = rh * (1.0f / 7.0f);
        int p = tid;
        float pos = (float)(p >> 1) + 0.25f + 0.5f * (float)(p & 1);
        float xs = b0 + pos * bw;
        float ysv = b1 + pos * bh;
        vxs[p] = (xs >= -1.0f && xs <= 14.0f);
        vys[p] = (ysv >= -1.0f && ysv <= 14.0f);
        float xc = fminf(fmaxf(xs, 0.0f), 13.0f);
        float yc = fminf(fmaxf(ysv, 0.0f), 13.0f);
        int x0 = (int)floorf(xc), y0 = (int)floorf(yc);
        x0s[p] = x0; y0s[p] = y0;
        x1s[p] = min(x0 + 1, 13); y1s[p] = min(y0 + 1, 13);
        float lx = xc - (float)x0, ly = yc - (float)y0;
        wx0s[p] = 1.0f - lx; wx1s[p] = lx; wy0s[p] = 1.0f - ly; wy1s[p] = ly;
    }
    for (int f4 = tid; f4 < 64 * 49; f4 += 256) {
        int c = f4 / 49, p = f4 % 49;
        float4 v = *(const float4*)(x_t + (size_t)(o0 + c) * 3136 + t * 196 + p * 4);
        float* d = sm + c * 197 + p * 4;
        d[0] = v.x; d[1] = v.y; d[2] = v.z; d[3] = v.w;
    }
    __syncthreads();
    for (int item = tid; item < 64 * 49; item += 256) {
        int c = item & 63, ij = item >> 6;
        int i = ij / 7, j = ij % 7;
        const float* base = &sm[c * 197];
        float sum = 0.0f;
#pragma unroll
        for (int s = 0; s < 2; ++s) {
            int p = 2 * i + s;
#pragma unroll
            for (int u = 0; u < 2; ++u) {
                int q = 2 * j + u;
                if (vys[p] && vxs[q]) {
                    float v00 = base[y0s[p] * 14 + x0s[q]];
                    float v01 = base[y0s[p] * 14 + x1s[q]];
                    float v10 = base[y1s[p] * 14 + x0s[q]];
                    float v11 = base[y1s[p] * 14 + x1s[q]];
                    sum += wy0s[p] * (wx0s[q] * v00 + wx1s[q] * v01) +
                           wy1s[p] * (wx0s[q] * v10 + wx1s[q] * v11);
                }
            }
        }
        mr[(size_t)(t * 49 + ij) * ND + o0 + c] = 0.25f * sum;
    }

    if (bid < 384) {
        // ---- packA: (t2, kc). Coalesced frame load of y into LDS, scatter even pixels.
        __syncthreads();              // done with sm's roi contents
        int t2 = bid / 24, kc = bid % 24;
        for (int f4 = tid; f4 < 64 * 49; f4 += 256) {
            int c = f4 / 49, p = f4 % 49;
            float4 v = *(const float4*)(y + (size_t)(kc * 64 + c) * 3136 + t2 * 196 + p * 4);
            float* d = sm + c * 197 + p * 4;
            d[0] = v.x; d[1] = v.y; d[2] = v.z; d[3] = v.w;
        }
        __syncthreads();
        for (int item = tid; item < 64 * 49; item += 256) {
            int c = item & 63, ij = item >> 6;
            int i = ij / 7, j = ij % 7;
            Ap[(size_t)(t2 * 49 + ij) * KD + kc * 64 + c] =
                f2bf(sm[c * 197 + (2 * i) * 14 + 2 * j]);
        }
    } else {
        // ---- packB: conv_w fp32 -> bf16, 384 blocks x 12288 elems, coalesced
        size_t base = (size_t)(bid - 384) * 12288;
#pragma unroll
        for (int v = 0; v < 12; ++v) {
            size_t e = base + v * 1024 + tid * 4;
            float4 w4 = *(const float4*)(conv_w + e);
            ushort4 o;
            o.x = f2bf(w4.x); o.y = f2bf(w4.y); o.z = f2bf(w4.z); o.w = f2bf(w4.w);
            *(ushort4*)(Bp + e) = o;
        }
        // ---- zerofill Ap rows 784..831: 9216 uint4 spread over 384 blocks (24 each)
        if (tid < 24) {
            uint4 z = {0u, 0u, 0u, 0u};
            ((uint4*)(Ap + (size_t)MD * KD))[(size_t)(bid - 384) * 24 + tid] = z;
        }
    }
}

// =============== phase B: t-aligned GEMM + BN + GELU + *mr + scatter + residual ===============
__device__ void phaseB(char* smraw,
                       const unsigned short* __restrict__ Ap,
                       const unsigned short* __restrict__ Bp,
                       const float* __restrict__ mr,
                       const float* __restrict__ x_t, const float* __restrict__ rois,
                       const float* __restrict__ cb, const float* __restrict__ gm,
                       const float* __restrict__ bt, const float* __restrict__ rm,
                       const float* __restrict__ rv,
                       float* __restrict__ out) {
    unsigned short* As0 = (unsigned short*)smraw;            // [2][64][72] = 18,432 B
    unsigned short* Bs0 = (unsigned short*)(smraw + 18432);  // [2][64][72]
    const int bid = blockIdx.x;
    const int tid = threadIdx.x;
    const int t = bid / 48;
    const int n0 = (bid % 48) * 64;
    const int m0g = t * 49;                                  // global A-row base (64 rows read, 49 kept)
    const int wave = tid >> 6;
    const int lane = tid & 63;
    const int wm = wave >> 1, wn = wave & 1;
    const int l15 = lane & 15, quad = lane >> 4;

    floatx4 acc00 = {0.f, 0.f, 0.f, 0.f}, acc01 = {0.f, 0.f, 0.f, 0.f};
    floatx4 acc10 = {0.f, 0.f, 0.f, 0.f}, acc11 = {0.f, 0.f, 0.f, 0.f};

    const int srow = tid >> 3;
    const int sko = (tid & 7) * 8;
    const float4* agp0 = (const float4*)(Ap + (size_t)(m0g + srow) * KD + sko);
    const float4* agp1 = (const float4*)(Ap + (size_t)(m0g + srow + 32) * KD + sko);
    const float4* bgp0 = (const float4*)(Bp + (size_t)(n0 + srow) * KD + sko);
    const float4* bgp1 = (const float4*)(Bp + (size_t)(n0 + srow + 32) * KD + sko);

    float4 av0 = agp0[0], av1 = agp1[0], bv0 = bgp0[0], bv1 = bgp1[0];

    int p = 0;
    for (int kt = 0; kt < KD; kt += 64, p ^= 1) {
        *(float4*)(&As0[p * 4608 + srow * 72 + sko]) = av0;
        *(float4*)(&As0[p * 4608 + (srow + 32) * 72 + sko]) = av1;
        *(float4*)(&Bs0[p * 4608 + srow * 72 + sko]) = bv0;
        *(float4*)(&Bs0[p * 4608 + (srow + 32) * 72 + sko]) = bv1;
        __syncthreads();
        if (kt + 64 < KD) {
            int q = (kt >> 3) + 8;
            av0 = agp0[q]; av1 = agp1[q]; bv0 = bgp0[q]; bv1 = bgp1[q];
        }
#pragma unroll
        for (int ko = 0; ko < 2; ++ko) {
            short8 a0 = *(const short8*)(&As0[p * 4608 + (wm * 32 + l15) * 72 + ko * 32 + quad * 8]);
            short8 a1 = *(const short8*)(&As0[p * 4608 + (wm * 32 + 16 + l15) * 72 + ko * 32 + quad * 8]);
            short8 b0 = *(const short8*)(&Bs0[p * 4608 + (wn * 32 + l15) * 72 + ko * 32 + quad * 8]);
            short8 b1 = *(const short8*)(&Bs0[p * 4608 + (wn * 32 + 16 + l15) * 72 + ko * 32 + quad * 8]);
            acc00 = __builtin_amdgcn_mfma_f32_16x16x32_bf16(a0, b0, acc00, 0, 0, 0);
            acc01 = __builtin_amdgcn_mfma_f32_16x16x32_bf16(a0, b1, acc01, 0, 0, 0);
            acc10 = __builtin_amdgcn_mfma_f32_16x16x32_bf16(a1, b0, acc10, 0, 0, 0);
            acc11 = __builtin_amdgcn_mfma_f32_16x16x32_bf16(a1, b1, acc11, 0, 0, 0);
        }
    }
    __syncthreads();                 // done with As/Bs; smraw becomes Wl

    // epilogue part 1: BN + GELU + *mr -> Wl[ij][n_local], pitch 65
    float* Wl = (float*)smraw;       // 49*65*4 = 12,740 B
#pragma unroll
    for (int ni = 0; ni < 2; ++ni) {
        int nl = wn * 32 + ni * 16 + l15;
        int n = n0 + nl;
        float scale = gm[n] / sqrtf(rv[n] + 1e-6f);
        float shift = (cb[n] - rm[n]) * scale + bt[n];
#pragma unroll
        for (int mi = 0; mi < 2; ++mi) {
            floatx4 a = (ni == 0) ? (mi == 0 ? acc00 : acc10) : (mi == 0 ? acc01 : acc11);
#pragma unroll
            for (int r = 0; r < 4; ++r) {
                int ml_ = wm * 32 + mi * 16 + quad * 4 + r;
                if (ml_ < 49) {
                    float v = a[r] * scale + shift;
                    float g = 0.5f * v * (1.0f + erff(v * 0.70710678118654752f));
                    Wl[ml_ * 65 + nl] = g * mr[(size_t)(m0g + ml_) * ND + n];
                }
            }
        }
    }
    __syncthreads();

    // epilogue part 2: out = x_t + scatter(Wl) for frame (t, n0..n0+63)
    float b0 = rois[t * 4 + 0] * 0.0625f, b1 = rois[t * 4 + 1] * 0.0625f;
    float b2 = rois[t * 4 + 2] * 0.0625f, b3 = rois[t * 4 + 3] * 0.0625f;
    int sxi = (int)floorf(b0), syi = (int)floorf(b1);
    int exi = (int)ceilf(b2), eyi = (int)ceilf(b3);
    int ml = (sxi + 7 < 14) ? sxi : exi - 7;
    int mt = (syi + 7 < 14) ? syi : eyi - 7;
    ml = min(max(ml, 0), 7);
    mt = min(max(mt, 0), 7);

    for (int i4 = tid; i4 < 64 * 49; i4 += 256) {
        int c = i4 / 49, p4 = i4 % 49;
        size_t e0 = (size_t)(n0 + c) * 3136 + t * 196 + p4 * 4;
        float4 xv = *(const float4*)(x_t + e0);
        float r[4] = {xv.x, xv.y, xv.z, xv.w};
#pragma unroll
        for (int u = 0; u < 4; ++u) {
            int pix = p4 * 4 + u;
            int h = pix / 14, w = pix % 14;
            int i = h - mt, j = w - ml;
            if (i >= 0 && i < 7 && j >= 0 && j < 7)
                r[u] += Wl[(i * 7 + j) * 65 + c];
        }
        *(float4*)(out + e0) = make_float4(r[0], r[1], r[2], r[3]);
    }
}

// =============== kernels ===============
__global__ __launch_bounds__(256, 3) void fused_k(const float* y, const float* x_t,
                                                  const float* rois, const float* conv_w,
                                                  const float* cb, const float* gm,
                                                  const float* bt, const float* rm,
                                                  const float* rv,
                                                  unsigned short* Ap, unsigned short* Bp,
                                                  float* mr, float* out) {
    __shared__ alignas(16) char smraw[50432];
    phaseA(smraw, y, x_t, rois, conv_w, Ap, Bp, mr);
    __threadfence();
    cg::this_grid().sync();
    phaseB(smraw, Ap, Bp, mr, x_t, rois, cb, gm, bt, rm, rv, out);
}

__global__ __launch_bounds__(256, 3) void prepA_k(const float* y, const float* x_t,
                                                  const float* rois, const float* conv_w,
                                                  unsigned short* Ap, unsigned short* Bp,
                                                  float* mr) {
    __shared__ alignas(16) char smraw[50432];
    phaseA(smraw, y, x_t, rois, conv_w, Ap, Bp, mr);
}

__global__ __launch_bounds__(256, 3) void gemmB_k(const unsigned short* Ap,
                                                  const unsigned short* Bp,
                                                  const float* mr, const float* x_t,
                                                  const float* rois, const float* cb,
                                                  const float* gm, const float* bt,
                                                  const float* rm, const float* rv,
                                                  float* out) {
    __shared__ alignas(16) char smraw[50432];
    phaseB(smraw, Ap, Bp, mr, x_t, rois, cb, gm, bt, rm, rv, out);
}

extern "C" void kernel_launch(void* const* d_in, const int* in_sizes, int n_in,
                              void* d_out, int out_size, void* d_ws, size_t ws_size,
                              hipStream_t stream) {
    const float* y = (const float*)d_in[0];
    const float* x_t = (const float*)d_in[1];
    const float* rois = (const float*)d_in[2];
    const float* conv_w = (const float*)d_in[3];
    const float* cb = (const float*)d_in[4];
    const float* gm = (const float*)d_in[5];
    const float* bt = (const float*)d_in[6];
    const float* rm = (const float*)d_in[7];
    const float* rv = (const float*)d_in[8];
    float* out = (float*)d_out;

    char* ws = (char*)d_ws;
    unsigned short* Ap = (unsigned short*)ws;                       // 832*1536*2
    unsigned short* Bp = (unsigned short*)(ws + 2555904);           // 3072*1536*2
    float* mr = (float*)(ws + 2555904 + 9437184);                   // 784*3072*4

    void* args[] = {(void*)&y, (void*)&x_t, (void*)&rois, (void*)&conv_w,
                    (void*)&cb, (void*)&gm, (void*)&bt, (void*)&rm, (void*)&rv,
                    (void*)&Ap, (void*)&Bp, (void*)&mr, (void*)&out};
    hipError_t err = hipLaunchCooperativeKernel((const void*)fused_k, dim3(GRID_N),
                                                dim3(256), args, 0, stream);
    if (err != hipSuccess) {
        // fallback: same phases, two plain dispatches
        prepA_k<<<GRID_N, 256, 0, stream>>>(y, x_t, rois, conv_w, Ap, Bp, mr);
        gemmB_k<<<GRID_N, 256, 0, stream>>>(Ap, Bp, mr, x_t, rois, cb, gm, bt, rm, rv, out);
    }
}

// Round 5
// 196.099 us; speedup vs baseline: 2.0441x; 2.0441x over previous
//
#include <hip/hip_runtime.h>

#define KD 1536
#define ND 3072
#define MD 784
#define MPAD 832
#define TT 16

typedef __attribute__((ext_vector_type(8))) short short8;
typedef __attribute__((ext_vector_type(4))) float floatx4;

__device__ __forceinline__ unsigned short f2bf(float f) {
    unsigned int x = __float_as_uint(f);
    unsigned int r = (x + 0x7fffu + ((x >> 16) & 1u)) >> 16;
    return (unsigned short)r;
}

// =============== prepA: packA (blocks 0..383) | packB + zerofill (384..767) ===============
__global__ __launch_bounds__(256, 3) void prepA_k(const float* __restrict__ y,
                                                  const float* __restrict__ conv_w,
                                                  unsigned short* __restrict__ Ap,
                                                  unsigned short* __restrict__ Bp) {
    __shared__ float sm[64 * 197];
    const int bid = blockIdx.x;
    const int tid = threadIdx.x;

    if (bid < 384) {
        // packA: block = (t, kc). Coalesced frame-major scalar read of y into LDS,
        // then scatter 49 even pixels to Ap[m][k] with lanes over k (coalesced).
        int t = bid / 24, kc = bid % 24;
        for (int f = tid; f < 64 * 196; f += 256) {
            int c = f / 196, pix = f % 196;
            sm[c * 197 + pix] = y[(size_t)(kc * 64 + c) * 3136 + t * 196 + pix];
        }
        __syncthreads();
        for (int item = tid; item < 64 * 49; item += 256) {
            int c = item & 63, ij = item >> 6;
            int i = ij / 7, j = ij % 7;
            Ap[(size_t)(t * 49 + ij) * KD + kc * 64 + c] =
                f2bf(sm[c * 197 + (2 * i) * 14 + 2 * j]);
        }
    } else {
        // packB: conv_w fp32 [o][c] -> bf16 [ND][KD], fully coalesced; 12288 elems/block
        size_t base = (size_t)(bid - 384) * 12288;
#pragma unroll
        for (int v = 0; v < 12; ++v) {
            size_t e = base + v * 1024 + tid * 4;
            float4 w4 = *(const float4*)(conv_w + e);
            ushort4 o;
            o.x = f2bf(w4.x); o.y = f2bf(w4.y); o.z = f2bf(w4.z); o.w = f2bf(w4.w);
            *(ushort4*)(Bp + e) = o;
        }
        // zerofill Ap rows 784..831: 9216 uint4 spread over 384 blocks (24 each)
        if (tid < 24) {
            uint4 z = {0u, 0u, 0u, 0u};
            ((uint4*)(Ap + (size_t)MD * KD))[(size_t)(bid - 384) * 24 + tid] = z;
        }
    }
}

// =============== gemmB: t-aligned GEMM + ROI(LDS) + BN + GELU + scatter + residual ===============
// block = (t, 64-channel chunk). LDS union:
//   K-loop:  As[2][64][72] + Bs[2][64][72] ushort  = 36,864 B   (in smraw[0..36864))
//   post:    frame f[64*197] float = 50,432 B      (smraw[0..50432))
//            mrl/Wl [49*65] float  = 12,740 B      (smraw[50432..63172))
__global__ __launch_bounds__(256, 2) void gemmB_k(const unsigned short* __restrict__ Ap,
                                                  const unsigned short* __restrict__ Bp,
                                                  const float* __restrict__ x_t,
                                                  const float* __restrict__ rois,
                                                  const float* __restrict__ cb,
                                                  const float* __restrict__ gm,
                                                  const float* __restrict__ bt,
                                                  const float* __restrict__ rm,
                                                  const float* __restrict__ rv,
                                                  float* __restrict__ out) {
    __shared__ alignas(16) char smraw[63232];
    __shared__ float wx0s[14], wx1s[14], wy0s[14], wy1s[14];
    __shared__ int x0s[14], x1s[14], y0s[14], y1s[14], vxs[14], vys[14];

    unsigned short* As0 = (unsigned short*)smraw;            // [2][64][72]
    unsigned short* Bs0 = (unsigned short*)(smraw + 18432);
    const int bid = blockIdx.x;
    const int tid = threadIdx.x;
    const int t = bid / 48;
    const int n0 = (bid % 48) * 64;
    const int m0g = t * 49;                 // 64 A-rows read; rows >= 49 discarded
    const int wave = tid >> 6;
    const int lane = tid & 63;
    const int wm = wave >> 1, wn = wave & 1;
    const int l15 = lane & 15, quad = lane >> 4;

    floatx4 acc00 = {0.f, 0.f, 0.f, 0.f}, acc01 = {0.f, 0.f, 0.f, 0.f};
    floatx4 acc10 = {0.f, 0.f, 0.f, 0.f}, acc11 = {0.f, 0.f, 0.f, 0.f};

    const int srow = tid >> 3;
    const int sko = (tid & 7) * 8;
    const float4* agp0 = (const float4*)(Ap + (size_t)(m0g + srow) * KD + sko);
    const float4* agp1 = (const float4*)(Ap + (size_t)(m0g + srow + 32) * KD + sko);
    const float4* bgp0 = (const float4*)(Bp + (size_t)(n0 + srow) * KD + sko);
    const float4* bgp1 = (const float4*)(Bp + (size_t)(n0 + srow + 32) * KD + sko);

    float4 av0 = agp0[0], av1 = agp1[0], bv0 = bgp0[0], bv1 = bgp1[0];

    int p = 0;
    for (int kt = 0; kt < KD; kt += 64, p ^= 1) {
        *(float4*)(&As0[p * 4608 + srow * 72 + sko]) = av0;
        *(float4*)(&As0[p * 4608 + (srow + 32) * 72 + sko]) = av1;
        *(float4*)(&Bs0[p * 4608 + srow * 72 + sko]) = bv0;
        *(float4*)(&Bs0[p * 4608 + (srow + 32) * 72 + sko]) = bv1;
        __syncthreads();
        if (kt + 64 < KD) {
            int q = (kt >> 3) + 8;
            av0 = agp0[q]; av1 = agp1[q]; bv0 = bgp0[q]; bv1 = bgp1[q];
        }
#pragma unroll
        for (int ko = 0; ko < 2; ++ko) {
            short8 a0 = *(const short8*)(&As0[p * 4608 + (wm * 32 + l15) * 72 + ko * 32 + quad * 8]);
            short8 a1 = *(const short8*)(&As0[p * 4608 + (wm * 32 + 16 + l15) * 72 + ko * 32 + quad * 8]);
            short8 b0 = *(const short8*)(&Bs0[p * 4608 + (wn * 32 + l15) * 72 + ko * 32 + quad * 8]);
            short8 b1 = *(const short8*)(&Bs0[p * 4608 + (wn * 32 + 16 + l15) * 72 + ko * 32 + quad * 8]);
            acc00 = __builtin_amdgcn_mfma_f32_16x16x32_bf16(a0, b0, acc00, 0, 0, 0);
            acc01 = __builtin_amdgcn_mfma_f32_16x16x32_bf16(a0, b1, acc01, 0, 0, 0);
            acc10 = __builtin_amdgcn_mfma_f32_16x16x32_bf16(a1, b0, acc10, 0, 0, 0);
            acc11 = __builtin_amdgcn_mfma_f32_16x16x32_bf16(a1, b1, acc11, 0, 0, 0);
        }
    }
    __syncthreads();                 // K-loop done; smraw becomes frame + mrl

    // ---- stage x_t frame (t, n0..n0+63) into LDS; consumed by ROI and residual
    float* fr = (float*)smraw;                    // [64][197]
    float* mrl = (float*)(smraw + 50432);         // [49][65], becomes Wl in place
    for (int f = tid; f < 64 * 196; f += 256) {
        int c = f / 196, pix = f % 196;
        fr[c * 197 + pix] = x_t[(size_t)(n0 + c) * 3136 + t * 196 + pix];
    }
    if (tid < 14) {
        float b0 = rois[t * 4 + 0] * 0.0625f, b1 = rois[t * 4 + 1] * 0.0625f;
        float b2 = rois[t * 4 + 2] * 0.0625f, b3 = rois[t * 4 + 3] * 0.0625f;
        float rw = fmaxf(b2 - b0, 1.0f), rh = fmaxf(b3 - b1, 1.0f);
        float bw = rw * (1.0f / 7.0f), bh = rh * (1.0f / 7.0f);
        int pp = tid;
        float pos = (float)(pp >> 1) + 0.25f + 0.5f * (float)(pp & 1);
        float xs = b0 + pos * bw;
        float ysv = b1 + pos * bh;
        vxs[pp] = (xs >= -1.0f && xs <= 14.0f);
        vys[pp] = (ysv >= -1.0f && ysv <= 14.0f);
        float xc = fminf(fmaxf(xs, 0.0f), 13.0f);
        float yc = fminf(fmaxf(ysv, 0.0f), 13.0f);
        int x0 = (int)floorf(xc), y0 = (int)floorf(yc);
        x0s[pp] = x0; y0s[pp] = y0;
        x1s[pp] = min(x0 + 1, 13); y1s[pp] = min(y0 + 1, 13);
        float lx = xc - (float)x0, ly = yc - (float)y0;
        wx0s[pp] = 1.0f - lx; wx1s[pp] = lx; wy0s[pp] = 1.0f - ly; wy1s[pp] = ly;
    }
    __syncthreads();

    // ---- ROI align from LDS frame -> mrl[ij][c_local] (pitch 65)
    for (int item = tid; item < 64 * 49; item += 256) {
        int c = item & 63, ij = item >> 6;
        int i = ij / 7, j = ij % 7;
        const float* base = &fr[c * 197];
        float sum = 0.0f;
#pragma unroll
        for (int s = 0; s < 2; ++s) {
            int pp = 2 * i + s;
#pragma unroll
            for (int u = 0; u < 2; ++u) {
                int q = 2 * j + u;
                if (vys[pp] && vxs[q]) {
                    float v00 = base[y0s[pp] * 14 + x0s[q]];
                    float v01 = base[y0s[pp] * 14 + x1s[q]];
                    float v10 = base[y1s[pp] * 14 + x0s[q]];
                    float v11 = base[y1s[pp] * 14 + x1s[q]];
                    sum += wy0s[pp] * (wx0s[q] * v00 + wx1s[q] * v01) +
                           wy1s[pp] * (wx0s[q] * v10 + wx1s[q] * v11);
                }
            }
        }
        mrl[ij * 65 + c] = 0.25f * sum;
    }
    __syncthreads();

    // ---- epilogue 1: BN + exact GELU, multiply mrl in place -> Wl
#pragma unroll
    for (int ni = 0; ni < 2; ++ni) {
        int nl = wn * 32 + ni * 16 + l15;
        int n = n0 + nl;
        float scale = gm[n] / sqrtf(rv[n] + 1e-6f);
        float shift = (cb[n] - rm[n]) * scale + bt[n];
#pragma unroll
        for (int mi = 0; mi < 2; ++mi) {
            floatx4 a = (ni == 0) ? (mi == 0 ? acc00 : acc10) : (mi == 0 ? acc01 : acc11);
#pragma unroll
            for (int r = 0; r < 4; ++r) {
                int ml_ = wm * 32 + mi * 16 + quad * 4 + r;
                if (ml_ < 49) {
                    float v = a[r] * scale + shift;
                    float g = 0.5f * v * (1.0f + erff(v * 0.70710678118654752f));
                    mrl[ml_ * 65 + nl] *= g;       // unique owner per element
                }
            }
        }
    }

    // ---- epilogue 2: out = frame + scatter(Wl), coalesced float4 stores
    float b0 = rois[t * 4 + 0] * 0.0625f, b1 = rois[t * 4 + 1] * 0.0625f;
    float b2 = rois[t * 4 + 2] * 0.0625f, b3 = rois[t * 4 + 3] * 0.0625f;
    int sxi = (int)floorf(b0), syi = (int)floorf(b1);
    int exi = (int)ceilf(b2), eyi = (int)ceilf(b3);
    int mlo = (sxi + 7 < 14) ? sxi : exi - 7;
    int mto = (syi + 7 < 14) ? syi : eyi - 7;
    mlo = min(max(mlo, 0), 7);
    mto = min(max(mto, 0), 7);
    __syncthreads();

    for (int i4 = tid; i4 < 64 * 49; i4 += 256) {
        int c = i4 / 49, p4 = i4 % 49;
        float r[4];
#pragma unroll
        for (int u = 0; u < 4; ++u) {
            int pix = p4 * 4 + u;
            float v = fr[c * 197 + pix];
            int h = pix / 14, w = pix % 14;
            int i = h - mto, j = w - mlo;
            if (i >= 0 && i < 7 && j >= 0 && j < 7)
                v += mrl[(i * 7 + j) * 65 + c];
            r[u] = v;
        }
        *(float4*)(out + (size_t)(n0 + c) * 3136 + t * 196 + p4 * 4) =
            make_float4(r[0], r[1], r[2], r[3]);
    }
}

extern "C" void kernel_launch(void* const* d_in, const int* in_sizes, int n_in,
                              void* d_out, int out_size, void* d_ws, size_t ws_size,
                              hipStream_t stream) {
    const float* y = (const float*)d_in[0];
    const float* x_t = (const float*)d_in[1];
    const float* rois = (const float*)d_in[2];
    const float* conv_w = (const float*)d_in[3];
    const float* cb = (const float*)d_in[4];
    const float* gm = (const float*)d_in[5];
    const float* bt = (const float*)d_in[6];
    const float* rm = (const float*)d_in[7];
    const float* rv = (const float*)d_in[8];
    float* out = (float*)d_out;

    char* ws = (char*)d_ws;
    unsigned short* Ap = (unsigned short*)ws;                 // 832*1536*2 = 2,555,904 B
    unsigned short* Bp = (unsigned short*)(ws + 2555904);     // 3072*1536*2 = 9,437,184 B

    prepA_k<<<768, 256, 0, stream>>>(y, conv_w, Ap, Bp);
    gemmB_k<<<768, 256, 0, stream>>>(Ap, Bp, x_t, rois, cb, gm, bt, rm, rv, out);
}

// Round 6
// 175.615 us; speedup vs baseline: 2.2825x; 1.1166x over previous
//
#include <hip/hip_runtime.h>

#define KD 1536
#define ND 3072
#define MD 784
#define TT 16

typedef __attribute__((ext_vector_type(8))) short short8;
typedef __attribute__((ext_vector_type(4))) float floatx4;

__device__ __forceinline__ unsigned short f2bf(float f) {
    unsigned int x = __float_as_uint(f);
    unsigned int r = (x + 0x7fffu + ((x >> 16) & 1u)) >> 16;
    return (unsigned short)r;
}

__device__ __forceinline__ void gld_lds16(const unsigned short* g, unsigned short* l) {
    __builtin_amdgcn_global_load_lds((const __attribute__((address_space(1))) void*)g,
                                     (__attribute__((address_space(3))) void*)l, 16, 0, 0);
}

// =============== prep: ROI (all 768 blocks) + packA (0..383) / packB (384..767) ===============
__global__ __launch_bounds__(256) void prep_k(const float* __restrict__ y,
                                              const float* __restrict__ x_t,
                                              const float* __restrict__ rois,
                                              const float* __restrict__ conv_w,
                                              unsigned short* __restrict__ Ap,
                                              unsigned short* __restrict__ Bp,
                                              float* __restrict__ mr) {
    __shared__ float sm[64 * 197];
    __shared__ float wx0s[14], wx1s[14], wy0s[14], wy1s[14];
    __shared__ int x0s[14], x1s[14], y0s[14], y1s[14], vxs[14], vys[14];
    const int bid = blockIdx.x;
    const int tid = threadIdx.x;

    // ---- ROI align for (t, o-chunk): x_t -> mr[m][ND], m = t*49 + ij
    const int t = bid / 48;
    const int o0 = (bid % 48) * 64;

    if (tid < 14) {
        float b0 = rois[t * 4 + 0] * 0.0625f, b1 = rois[t * 4 + 1] * 0.0625f;
        float b2 = rois[t * 4 + 2] * 0.0625f, b3 = rois[t * 4 + 3] * 0.0625f;
        float rw = fmaxf(b2 - b0, 1.0f), rh = fmaxf(b3 - b1, 1.0f);
        float bw = rw * (1.0f / 7.0f), bh = rh * (1.0f / 7.0f);
        int p = tid;
        float pos = (float)(p >> 1) + 0.25f + 0.5f * (float)(p & 1);
        float xs = b0 + pos * bw;
        float ysv = b1 + pos * bh;
        vxs[p] = (xs >= -1.0f && xs <= 14.0f);
        vys[p] = (ysv >= -1.0f && ysv <= 14.0f);
        float xc = fminf(fmaxf(xs, 0.0f), 13.0f);
        float yc = fminf(fmaxf(ysv, 0.0f), 13.0f);
        int x0 = (int)floorf(xc), y0 = (int)floorf(yc);
        x0s[p] = x0; y0s[p] = y0;
        x1s[p] = min(x0 + 1, 13); y1s[p] = min(y0 + 1, 13);
        float lx = xc - (float)x0, ly = yc - (float)y0;
        wx0s[p] = 1.0f - lx; wx1s[p] = lx; wy0s[p] = 1.0f - ly; wy1s[p] = ly;
    }
    for (int f = tid; f < 64 * 196; f += 256) {
        int c = f / 196, pix = f % 196;
        sm[c * 197 + pix] = x_t[(size_t)(o0 + c) * 3136 + t * 196 + pix];
    }
    __syncthreads();
    for (int item = tid; item < 64 * 49; item += 256) {
        int c = item & 63, ij = item >> 6;
        int i = ij / 7, j = ij % 7;
        const float* base = &sm[c * 197];
        float sum = 0.0f;
#pragma unroll
        for (int s = 0; s < 2; ++s) {
            int p = 2 * i + s;
#pragma unroll
            for (int u = 0; u < 2; ++u) {
                int q = 2 * j + u;
                if (vys[p] && vxs[q]) {
                    float v00 = base[y0s[p] * 14 + x0s[q]];
                    float v01 = base[y0s[p] * 14 + x1s[q]];
                    float v10 = base[y1s[p] * 14 + x0s[q]];
                    float v11 = base[y1s[p] * 14 + x1s[q]];
                    sum += wy0s[p] * (wx0s[q] * v00 + wx1s[q] * v01) +
                           wy1s[p] * (wx0s[q] * v10 + wx1s[q] * v11);
                }
            }
        }
        mr[(size_t)(t * 49 + ij) * ND + o0 + c] = 0.25f * sum;
    }

    if (bid < 384) {
        // ---- packA: block = (t2, kc). Coalesced frame read into LDS, scatter even pixels.
        __syncthreads();
        int t2 = bid / 24, kc = bid % 24;
        for (int f = tid; f < 64 * 196; f += 256) {
            int c = f / 196, pix = f % 196;
            sm[c * 197 + pix] = y[(size_t)(kc * 64 + c) * 3136 + t2 * 196 + pix];
        }
        __syncthreads();
        for (int item = tid; item < 64 * 49; item += 256) {
            int c = item & 63, ij = item >> 6;
            int i = ij / 7, j = ij % 7;
            Ap[(size_t)(t2 * 49 + ij) * KD + kc * 64 + c] =
                f2bf(sm[c * 197 + (2 * i) * 14 + 2 * j]);
        }
    } else {
        // ---- packB: conv_w fp32 [o][c] -> bf16 [ND][KD], fully coalesced
        size_t base = (size_t)(bid - 384) * 12288;
#pragma unroll
        for (int v = 0; v < 12; ++v) {
            size_t e = base + v * 1024 + tid * 4;
            float4 w4 = *(const float4*)(conv_w + e);
            ushort4 o;
            o.x = f2bf(w4.x); o.y = f2bf(w4.y); o.z = f2bf(w4.z); o.w = f2bf(w4.w);
            *(ushort4*)(Bp + e) = o;
        }
        // no zerofill: gemm discards rows >= MD (poison there is benign)
    }
}

// =============== gemm: 64x64 tile, BK=64, global_load_lds(16B) dbuf, 1 barrier/iter ===============
// LDS layout: pitch 64 ushorts (no pad); 16B chunk for (row, logical L) stored at
// phys chunk P = L ^ (row & 7)  -> ds_read_b128 frag reads are 2-way max (free).
// Loader lane (prow=lane>>3, pch=lane&7) writes phys chunk pch of row prow, so it
// fetches logical L = pch ^ (prow & 7) from global (per-lane source address).
__global__ __launch_bounds__(256, 4) void gemm_k(const unsigned short* __restrict__ Ap,
                                                 const unsigned short* __restrict__ Bp,
                                                 const float* __restrict__ cb,
                                                 const float* __restrict__ gm,
                                                 const float* __restrict__ bt,
                                                 const float* __restrict__ rm,
                                                 const float* __restrict__ rv,
                                                 float* __restrict__ mrW) {
    __shared__ unsigned short As[2][64 * 64];
    __shared__ unsigned short Bs[2][64 * 64];
    const int tid = threadIdx.x;
    const int n0 = blockIdx.x * 64;
    const int m0 = blockIdx.y * 64;
    const int wv = tid >> 6;
    const int lane = tid & 63;
    const int wm = wv >> 1, wn = wv & 1;
    const int l15 = lane & 15, quad = lane >> 4;
    const int prow = lane >> 3, pch = lane & 7;
    const int L = pch ^ (prow & 7);

    // staging assignment: wv0 -> A rows 0..31, wv1 -> A rows 32..63,
    //                     wv2 -> B rows 0..31, wv3 -> B rows 32..63
    const unsigned short* gbase;
    unsigned short *lb0, *lb1;
    if (wv < 2) {
        gbase = Ap + (size_t)(m0 + wv * 32 + prow) * KD + L * 8;
        lb0 = &As[0][(wv * 32) * 64];
        lb1 = &As[1][(wv * 32) * 64];
    } else {
        gbase = Bp + (size_t)(n0 + (wv - 2) * 32 + prow) * KD + L * 8;
        lb0 = &Bs[0][((wv - 2) * 32) * 64];
        lb1 = &Bs[1][((wv - 2) * 32) * 64];
    }

    floatx4 acc00 = {0.f, 0.f, 0.f, 0.f}, acc01 = {0.f, 0.f, 0.f, 0.f};
    floatx4 acc10 = {0.f, 0.f, 0.f, 0.f}, acc11 = {0.f, 0.f, 0.f, 0.f};

    // preload tile 0 into buffer 0
#pragma unroll
    for (int j = 0; j < 4; ++j)
        gld_lds16(gbase + (size_t)j * 8 * KD, lb0 + j * 512);

    int p = 0;
    for (int kt = 0; kt < KD; kt += 64, p ^= 1) {
        __syncthreads();   // drains DMA into buf p; also orders vs prior reads of buf p^1
        if (kt + 64 < KD) {
            unsigned short* lb = p ? lb0 : lb1;          // next buffer = p^1
            const unsigned short* gb = gbase + kt + 64;
#pragma unroll
            for (int j = 0; j < 4; ++j)
                gld_lds16(gb + (size_t)j * 8 * KD, lb + j * 512);
        }
        const unsigned short* Ab = &As[p][0];
        const unsigned short* Bb = &Bs[p][0];
#pragma unroll
        for (int ko = 0; ko < 2; ++ko) {
            int ch = ((ko * 4 + quad) ^ (l15 & 7)) * 8;  // phys chunk offset (ushorts)
            short8 a0 = *(const short8*)(Ab + (wm * 32 + l15) * 64 + ch);
            short8 a1 = *(const short8*)(Ab + (wm * 32 + 16 + l15) * 64 + ch);
            short8 b0 = *(const short8*)(Bb + (wn * 32 + l15) * 64 + ch);
            short8 b1 = *(const short8*)(Bb + (wn * 32 + 16 + l15) * 64 + ch);
            acc00 = __builtin_amdgcn_mfma_f32_16x16x32_bf16(a0, b0, acc00, 0, 0, 0);
            acc01 = __builtin_amdgcn_mfma_f32_16x16x32_bf16(a0, b1, acc01, 0, 0, 0);
            acc10 = __builtin_amdgcn_mfma_f32_16x16x32_bf16(a1, b0, acc10, 0, 0, 0);
            acc11 = __builtin_amdgcn_mfma_f32_16x16x32_bf16(a1, b1, acc11, 0, 0, 0);
        }
    }

    // epilogue: BN + exact GELU, multiply mr in place -> W (same buffer, unique owner)
#pragma unroll
    for (int ni = 0; ni < 2; ++ni) {
        int n = n0 + wn * 32 + ni * 16 + l15;
        float scale = gm[n] / sqrtf(rv[n] + 1e-6f);
        float shift = (cb[n] - rm[n]) * scale + bt[n];
#pragma unroll
        for (int mi = 0; mi < 2; ++mi) {
            floatx4 a = (ni == 0) ? (mi == 0 ? acc00 : acc10) : (mi == 0 ? acc01 : acc11);
#pragma unroll
            for (int r = 0; r < 4; ++r) {
                int m = m0 + wm * 32 + mi * 16 + quad * 4 + r;
                if (m < MD) {
                    float v = a[r] * scale + shift;
                    float g = 0.5f * v * (1.0f + erff(v * 0.70710678118654752f));
                    size_t idx = (size_t)m * ND + n;
                    mrW[idx] = g * mrW[idx];
                }
            }
        }
    }
}

// =============== finalize: out = x_t + scatter(W); block = (t, 64-channel chunk) ===============
__global__ __launch_bounds__(256) void final_k(const float* __restrict__ x_t,
                                               const float* __restrict__ rois,
                                               const float* __restrict__ W,
                                               float* __restrict__ out) {
    __shared__ float Wl[49 * 65];   // pitch 65: conflict-free
    const int o0 = blockIdx.x * 64;
    const int t = blockIdx.y;
    const int tid = threadIdx.x;

    float b0 = rois[t * 4 + 0] * 0.0625f, b1 = rois[t * 4 + 1] * 0.0625f;
    float b2 = rois[t * 4 + 2] * 0.0625f, b3 = rois[t * 4 + 3] * 0.0625f;
    int sxi = (int)floorf(b0), syi = (int)floorf(b1);
    int exi = (int)ceilf(b2), eyi = (int)ceilf(b3);
    int ml = (sxi + 7 < 14) ? sxi : exi - 7;
    int mt = (syi + 7 < 14) ? syi : eyi - 7;
    ml = min(max(ml, 0), 7);
    mt = min(max(mt, 0), 7);

    for (int idx = tid; idx < 49 * 64; idx += 256) {
        int c = idx & 63, ij = idx >> 6;
        Wl[ij * 65 + c] = W[(size_t)(t * 49 + ij) * ND + o0 + c];
    }
    __syncthreads();

    for (int i4 = tid; i4 < 3136; i4 += 256) {
        int c = i4 / 49, p4 = i4 % 49;
        size_t e0 = (size_t)(o0 + c) * 3136 + t * 196 + p4 * 4;
        float4 xv = *(const float4*)(x_t + e0);
        float r[4] = {xv.x, xv.y, xv.z, xv.w};
#pragma unroll
        for (int u = 0; u < 4; ++u) {
            int pix = p4 * 4 + u;
            int h = pix / 14, w = pix % 14;
            int i = h - mt, j = w - ml;
            if (i >= 0 && i < 7 && j >= 0 && j < 7)
                r[u] += Wl[(i * 7 + j) * 65 + c];
        }
        *(float4*)(out + e0) = make_float4(r[0], r[1], r[2], r[3]);
    }
}

extern "C" void kernel_launch(void* const* d_in, const int* in_sizes, int n_in,
                              void* d_out, int out_size, void* d_ws, size_t ws_size,
                              hipStream_t stream) {
    const float* y = (const float*)d_in[0];
    const float* x_t = (const float*)d_in[1];
    const float* rois = (const float*)d_in[2];
    const float* conv_w = (const float*)d_in[3];
    const float* cb = (const float*)d_in[4];
    const float* gm = (const float*)d_in[5];
    const float* bt = (const float*)d_in[6];
    const float* rm = (const float*)d_in[7];
    const float* rv = (const float*)d_in[8];
    float* out = (float*)d_out;

    char* ws = (char*)d_ws;
    unsigned short* Ap = (unsigned short*)ws;                 // 832*1536*2 = 2,555,904 B (rows>=784 poison, unused)
    unsigned short* Bp = (unsigned short*)(ws + 2555904);     // 3072*1536*2 = 9,437,184 B
    float* mrW = (float*)(ws + 2555904 + 9437184);            // 784*3072*4 = 9,633,792 B

    prep_k<<<768, 256, 0, stream>>>(y, x_t, rois, conv_w, Ap, Bp, mrW);
    gemm_k<<<dim3(ND / 64, 13), 256, 0, stream>>>(Ap, Bp, cb, gm, bt, rm, rv, mrW);
    final_k<<<dim3(ND / 64, TT), 256, 0, stream>>>(x_t, rois, mrW, out);
}